// Round 12
// baseline (253.608 us; speedup 1.0000x reference)
//
#include <hip/hip_runtime.h>
#include <cstdint>
#include <cmath>

#define NN 100000      // nodes
#define NC 8           // communities
#define NF 256         // features (and D)
#define XPARTS_FLOATS ((size_t)NC * NN * NF)   // 204,800,000
#define XPARTS_VEC    ((size_t)XPARTS_FLOATS / 4)  // 51,200,000 f32x4
#define PLANE_VEC ((size_t)NN * 64)            // f32x4 per community plane

typedef float f32x4 __attribute__((ext_vector_type(4)));

// ---- K1: phi_raw[n][c] = mean(z[n, c*32:(c+1)*32]) in fp64, coalesced -----
__global__ __launch_bounds__(256) void k_phi_raw(const f32x4* __restrict__ z4,
                                                 double* __restrict__ raw) {
    int gid = blockIdx.x * 256 + threadIdx.x;
    int n = gid >> 6;
    int l = gid & 63;
    if (n >= NN) return;
    f32x4 v = z4[(size_t)n * 64 + l];
    double s = ((double)v.x + (double)v.y) + ((double)v.z + (double)v.w);
    s += __shfl_xor(s, 1, 64);
    s += __shfl_xor(s, 2, 64);
    s += __shfl_xor(s, 4, 64);
    if ((l & 7) == 0) raw[(size_t)n * NC + (l >> 3)] = s * (1.0 / 32.0);
}

// ---- K2: per-block column sum-of-exp partials (max-free, fp64) ------------
// raw = mean of 32 N(0,1) -> |raw| < ~0.5, exp never overflows: no max needed.
__global__ __launch_bounds__(256) void k_col_partial(const double* __restrict__ raw,
                                                     double* __restrict__ part) {
    __shared__ double ss[256][NC];
    int tid = threadIdx.x;
    int gtid = blockIdx.x * 256 + tid;
    double s[NC];
#pragma unroll
    for (int c = 0; c < NC; ++c) s[c] = 0.0;
    for (int n = gtid; n < NN; n += 256 * 256) {
        const double* rp = raw + (size_t)n * NC;
#pragma unroll
        for (int c = 0; c < NC; ++c) s[c] += exp(rp[c]);
    }
#pragma unroll
    for (int c = 0; c < NC; ++c) ss[tid][c] = s[c];
    __syncthreads();
    for (int off = 128; off > 0; off >>= 1) {
        if (tid < off) {
#pragma unroll
            for (int c = 0; c < NC; ++c) ss[tid][c] += ss[tid + off][c];
        }
        __syncthreads();
    }
    if (tid == 0) {
#pragma unroll
        for (int c = 0; c < NC; ++c) part[(size_t)blockIdx.x * NC + c] = ss[0][c];
    }
}

// ---- K3: merge 256 block partials -> final S_c ----------------------------
__global__ __launch_bounds__(256) void k_col_final(const double* __restrict__ part,
                                                   double* __restrict__ fin) {
    __shared__ double ss[256][NC];
    int tid = threadIdx.x;
#pragma unroll
    for (int c = 0; c < NC; ++c) ss[tid][c] = part[(size_t)tid * NC + c];
    __syncthreads();
    for (int off = 128; off > 0; off >>= 1) {
        if (tid < off) {
#pragma unroll
            for (int c = 0; c < NC; ++c) ss[tid][c] += ss[tid + off][c];
        }
        __syncthreads();
    }
    if (tid == 0) {
#pragma unroll
        for (int c = 0; c < NC; ++c) fin[c] = ss[0][c];
    }
}

// ---- K4: per-node mask (fp64), 0/1 floats to the output tail --------------
__global__ __launch_bounds__(256) void k_mask(const double* __restrict__ raw,
                                              const double* __restrict__ fin,
                                              float* __restrict__ mask_out) {
    int n = blockIdx.x * blockDim.x + threadIdx.x;
    if (n >= NN) return;
    double phi[NC];
    double r = 0.0;
#pragma unroll
    for (int c = 0; c < NC; ++c) {
        phi[c] = exp(raw[(size_t)n * NC + c]) / fin[c];
        r += phi[c];
    }
    double f = 8.0 - r;   // global sum of rowsums == 8 exactly
    double w[NC];
    double wmax = -1e300;
#pragma unroll
    for (int c = 0; c < NC; ++c) { w[c] = phi[c] * f; wmax = fmax(wmax, w[c]); }
#pragma unroll
    for (int c = 0; c < NC; ++c) {
        bool bit = (w[c] == wmax) || (w[c] >= 1.0);
        mask_out[(size_t)n * NC + c] = bit ? 1.0f : 0.0f;
    }
}

// ---- K5: unconditional zero-fill — no mask, no branch, no LDS --------------
// Grid-stride, lane-consecutive 16B nt stores: the pure-write configuration
// class that the 6.7 TB/s harness fill demonstrates. Isolates "write path"
// from "mask-dependent holes/branches".
__global__ __launch_bounds__(256) void k_fill_all(f32x4* __restrict__ out4) {
    size_t stride = (size_t)gridDim.x * 256;
    const f32x4 zz = (f32x4)(0.f);
    for (size_t i = (size_t)blockIdx.x * 256 + threadIdx.x; i < XPARTS_VEC; i += stride)
        __builtin_nontemporal_store(zz, &out4[i]);
}

// ---- K6: row-copy — one wave per row, overwrite masked rows with x --------
// (R7-proven config: plain x loads, nt stores)
__global__ __launch_bounds__(256) void k_copy(const f32x4* __restrict__ x4,
                                              const float* __restrict__ mask,
                                              f32x4* __restrict__ out4) {
    int gid = blockIdx.x * 256 + threadIdx.x;
    int n = gid >> 6;
    int lane = gid & 63;
    if (n >= NN) return;
    f32x4 v = x4[(size_t)n * 64 + lane];
    const f32x4* m4 = (const f32x4*)(mask + (size_t)n * NC);
    f32x4 m0 = m4[0], m1 = m4[1];                       // broadcast L1 reads
    float mm[NC] = {m0.x, m0.y, m0.z, m0.w, m1.x, m1.y, m1.z, m1.w};
    size_t rbase = (size_t)n * 64 + lane;
#pragma unroll
    for (int c = 0; c < NC; ++c) {
        if (mm[c] != 0.0f)                              // wave-uniform branch
            __builtin_nontemporal_store(v, &out4[(size_t)c * PLANE_VEC + rbase]);
    }
}

extern "C" void kernel_launch(void* const* d_in, const int* in_sizes, int n_in,
                              void* d_out, int out_size, void* d_ws, size_t ws_size,
                              hipStream_t stream) {
    const f32x4* x4 = (const f32x4*)d_in[0];
    const f32x4* z4 = (const f32x4*)d_in[1];
    float* out = (float*)d_out;
    float* mask_out = out + XPARTS_FLOATS;

    const size_t RAW_BYTES  = (size_t)NN * NC * sizeof(double);   // 6.4 MB
    const size_t PART_BYTES = 256 * NC * sizeof(double);          // 16 KB
    const size_t FIN_BYTES  = NC * sizeof(double);

    double *raw, *part, *fin;
    if (ws_size >= RAW_BYTES + PART_BYTES + FIN_BYTES) {
        raw  = (double*)d_ws;
        part = (double*)((char*)d_ws + RAW_BYTES);
        fin  = (double*)((char*)d_ws + RAW_BYTES + PART_BYTES);
    } else {
        // scratch carved from x_parts region of d_out; dead after K4 and
        // wiped by k_fill_all before k_copy writes the masked rows
        raw  = (double*)out;
        part = (double*)(out + 2000000);
        fin  = (double*)(out + 2200000);
    }

    k_phi_raw    <<<(NN * 64 + 255) / 256, 256, 0, stream>>>(z4, raw);
    k_col_partial<<<256, 256, 0, stream>>>(raw, part);
    k_col_final  <<<1, 256, 0, stream>>>(part, fin);
    k_mask       <<<(NN + 255) / 256, 256, 0, stream>>>(raw, fin, mask_out);
    k_fill_all   <<<2048, 256, 0, stream>>>((f32x4*)out);
    k_copy       <<<(NN * 64) / 256, 256, 0, stream>>>(x4, mask_out, (f32x4*)out);
}

// Round 13
// 195.079 us; speedup vs baseline: 1.3000x; 1.3000x over previous
//
#include <hip/hip_runtime.h>
#include <cstdint>
#include <cmath>

#define NN 100000      // nodes
#define NC 8           // communities
#define NF 256         // features (and D)
#define XPARTS_FLOATS ((size_t)NC * NN * NF)   // 204,800,000
#define PLANE_VEC ((size_t)NN * 64)            // f32x4 per community plane
#define CHUNK_ROWS 32                          // rows per fill block
#define NCHUNK (NN / CHUNK_ROWS)               // 3125 exact

typedef float f32x4 __attribute__((ext_vector_type(4)));

// ---- K1: phi_raw[n][c] = mean(z[n, c*32:(c+1)*32]) in fp64, coalesced -----
__global__ __launch_bounds__(256) void k_phi_raw(const f32x4* __restrict__ z4,
                                                 double* __restrict__ raw) {
    int gid = blockIdx.x * 256 + threadIdx.x;
    int n = gid >> 6;
    int l = gid & 63;
    if (n >= NN) return;
    f32x4 v = z4[(size_t)n * 64 + l];
    double s = ((double)v.x + (double)v.y) + ((double)v.z + (double)v.w);
    s += __shfl_xor(s, 1, 64);
    s += __shfl_xor(s, 2, 64);
    s += __shfl_xor(s, 4, 64);
    if ((l & 7) == 0) raw[(size_t)n * NC + (l >> 3)] = s * (1.0 / 32.0);
}

// ---- K2: per-block column sum-of-exp partials (max-free, fp64) ------------
// raw = mean of 32 N(0,1) -> |raw| < ~0.5, exp never overflows: no max needed.
__global__ __launch_bounds__(256) void k_col_partial(const double* __restrict__ raw,
                                                     double* __restrict__ part) {
    __shared__ double ss[256][NC];
    int tid = threadIdx.x;
    int gtid = blockIdx.x * 256 + tid;
    double s[NC];
#pragma unroll
    for (int c = 0; c < NC; ++c) s[c] = 0.0;
    for (int n = gtid; n < NN; n += 256 * 256) {
        const double* rp = raw + (size_t)n * NC;
#pragma unroll
        for (int c = 0; c < NC; ++c) s[c] += exp(rp[c]);
    }
#pragma unroll
    for (int c = 0; c < NC; ++c) ss[tid][c] = s[c];
    __syncthreads();
    for (int off = 128; off > 0; off >>= 1) {
        if (tid < off) {
#pragma unroll
            for (int c = 0; c < NC; ++c) ss[tid][c] += ss[tid + off][c];
        }
        __syncthreads();
    }
    if (tid == 0) {
#pragma unroll
        for (int c = 0; c < NC; ++c) part[(size_t)blockIdx.x * NC + c] = ss[0][c];
    }
}

// ---- K3: merge 256 block partials -> final S_c ----------------------------
__global__ __launch_bounds__(256) void k_col_final(const double* __restrict__ part,
                                                   double* __restrict__ fin) {
    __shared__ double ss[256][NC];
    int tid = threadIdx.x;
#pragma unroll
    for (int c = 0; c < NC; ++c) ss[tid][c] = part[(size_t)tid * NC + c];
    __syncthreads();
    for (int off = 128; off > 0; off >>= 1) {
        if (tid < off) {
#pragma unroll
            for (int c = 0; c < NC; ++c) ss[tid][c] += ss[tid + off][c];
        }
        __syncthreads();
    }
    if (tid == 0) {
#pragma unroll
        for (int c = 0; c < NC; ++c) fin[c] = ss[0][c];
    }
}

// ---- K4: per-node mask (fp64), 0/1 floats to the output tail --------------
__global__ __launch_bounds__(256) void k_mask(const double* __restrict__ raw,
                                              const double* __restrict__ fin,
                                              float* __restrict__ mask_out) {
    int n = blockIdx.x * blockDim.x + threadIdx.x;
    if (n >= NN) return;
    double phi[NC];
    double r = 0.0;
#pragma unroll
    for (int c = 0; c < NC; ++c) {
        phi[c] = exp(raw[(size_t)n * NC + c]) / fin[c];
        r += phi[c];
    }
    double f = 8.0 - r;   // global sum of rowsums == 8 exactly
    double w[NC];
    double wmax = -1e300;
#pragma unroll
    for (int c = 0; c < NC; ++c) { w[c] = phi[c] * f; wmax = fmax(wmax, w[c]); }
#pragma unroll
    for (int c = 0; c < NC; ++c) {
        bool bit = (w[c] == wmax) || (w[c] >= 1.0);
        mask_out[(size_t)n * NC + c] = bit ? 1.0f : 0.0f;
    }
}

// ---- K5a: hole-fill — pure-write zeros at every unmasked row --------------
// bid = c*NCHUNK + chunk: consecutive blocks write consecutive 32 KB chunks of
// the same plane -> 8 long sequential write streams. Reads only 32 mask floats.
__global__ __launch_bounds__(256) void k_fill_holes(const float* __restrict__ mask,
                                                    f32x4* __restrict__ out4) {
    int bid = blockIdx.x;
    int c = bid / NCHUNK;
    int chunk = bid - c * NCHUNK;
    int r0 = chunk * CHUNK_ROWS;
    int tid = threadIdx.x;
    __shared__ float bits[CHUNK_ROWS];
    if (tid < CHUNK_ROWS) bits[tid] = mask[(size_t)(r0 + tid) * NC + c];
    __syncthreads();
    size_t obase = (size_t)c * PLANE_VEC + (size_t)r0 * 64;
    const f32x4 zz = (f32x4)(0.f);
#pragma unroll
    for (int i = 0; i < (CHUNK_ROWS * 64) / 256; ++i) {
        int idx = i * 256 + tid;
        if (bits[idx >> 6] == 0.0f)                     // wave-uniform branch
            __builtin_nontemporal_store(zz, &out4[obase + idx]);
    }
}

// ---- K5b: row-copy — one wave per row, store x into each masked plane -----
__global__ __launch_bounds__(256) void k_copy(const f32x4* __restrict__ x4,
                                              const float* __restrict__ mask,
                                              f32x4* __restrict__ out4) {
    int gid = blockIdx.x * 256 + threadIdx.x;
    int n = gid >> 6;
    int lane = gid & 63;
    if (n >= NN) return;
    f32x4 v = x4[(size_t)n * 64 + lane];
    const f32x4* m4 = (const f32x4*)(mask + (size_t)n * NC);
    f32x4 m0 = m4[0], m1 = m4[1];                       // broadcast L1 reads
    float mm[NC] = {m0.x, m0.y, m0.z, m0.w, m1.x, m1.y, m1.z, m1.w};
    size_t rbase = (size_t)n * 64 + lane;
#pragma unroll
    for (int c = 0; c < NC; ++c) {
        if (mm[c] != 0.0f)                              // wave-uniform branch
            __builtin_nontemporal_store(v, &out4[(size_t)c * PLANE_VEC + rbase]);
    }
}

extern "C" void kernel_launch(void* const* d_in, const int* in_sizes, int n_in,
                              void* d_out, int out_size, void* d_ws, size_t ws_size,
                              hipStream_t stream) {
    const f32x4* x4 = (const f32x4*)d_in[0];
    const f32x4* z4 = (const f32x4*)d_in[1];
    float* out = (float*)d_out;
    float* mask_out = out + XPARTS_FLOATS;

    const size_t RAW_BYTES  = (size_t)NN * NC * sizeof(double);   // 6.4 MB
    const size_t PART_BYTES = 256 * NC * sizeof(double);          // 16 KB
    const size_t FIN_BYTES  = NC * sizeof(double);

    double *raw, *part, *fin;
    if (ws_size >= RAW_BYTES + PART_BYTES + FIN_BYTES) {
        raw  = (double*)d_ws;
        part = (double*)((char*)d_ws + RAW_BYTES);
        fin  = (double*)((char*)d_ws + RAW_BYTES + PART_BYTES);
    } else {
        // scratch carved from x_parts region of d_out; dead after K4, then
        // every byte is rewritten by exactly one of K5a (bit=0) / K5b (bit=1)
        raw  = (double*)out;
        part = (double*)(out + 2000000);
        fin  = (double*)(out + 2200000);
    }

    k_phi_raw    <<<(NN * 64 + 255) / 256, 256, 0, stream>>>(z4, raw);
    k_col_partial<<<256, 256, 0, stream>>>(raw, part);
    k_col_final  <<<1, 256, 0, stream>>>(part, fin);
    k_mask       <<<(NN + 255) / 256, 256, 0, stream>>>(raw, fin, mask_out);
    k_fill_holes <<<NC * NCHUNK, 256, 0, stream>>>(mask_out, (f32x4*)out);
    k_copy       <<<(NN * 64) / 256, 256, 0, stream>>>(x4, mask_out, (f32x4*)out);
}